// Round 9
// baseline (85.632 us; speedup 1.0000x reference)
//
#include <hip/hip_runtime.h>
#include <hip/hip_bf16.h>
#include <stdint.h>

// MatmulAttention: x = [2,16,2048,64] f32, q=k=v=x, no 1/sqrt(d) scale.
// out = softmax(q k^T) v, f32.
// R9 = R8 base, minus kv-split (net-negative: merge + 32MB partials for zero
// attn gain), plus two MFMA-side VALU cuts:
//   (a) C-init = -m: S accumulators start at -m (exact), deleting 32 subs/iter.
//   (b) l via ones-MFMA: l_acc = mfma(pa, ones, l_acc) -> row-sums land in
//       exactly the epilogue's register layout; deletes the 32-add serial
//       reduction + all shfls for l.

typedef __bf16 bf16x8 __attribute__((ext_vector_type(8)));
typedef __bf16 bf16x4 __attribute__((ext_vector_type(4)));
typedef __bf16 bf16x2 __attribute__((ext_vector_type(2)));
typedef float f32x4 __attribute__((ext_vector_type(4)));
typedef float f32x16 __attribute__((ext_vector_type(16)));
typedef unsigned int u32x4v __attribute__((ext_vector_type(4)));

#define SEQ 2048
#define HD 64
#define KVB 64
#define NBH 32
#define NTILE (SEQ / KVB)        // 32 kv tiles
#define IMG_BYTES 8192           // one 64x64 bf16 tile image
#define PAIR_BYTES 16384         // K image + VT image
#define IMG_TOT ((size_t)NBH * NTILE * PAIR_BYTES)          // 16 MB
#define WS_IMG IMG_TOT

#define QPB 128                  // q rows per block (32 per wave, 4 waves)

// 16B swizzle (R1 fallback kernel only)
__device__ __forceinline__ int swz(int row, int byteoff) {
    return byteoff ^ ((row & 7) << 4);
}

__device__ __forceinline__ float fexp2(float x) {
    float r;
    asm("v_exp_f32 %0, %1" : "=v"(r) : "v"(x));
    return r;
}

__device__ __forceinline__ unsigned pk_bf16(float a, float b) {
    bf16x2 v;
    v[0] = (__bf16)a;
    v[1] = (__bf16)b;
    return __builtin_bit_cast(unsigned, v);
}

// swz8: chunk c (8B, cols 4c..4c+3) of row r lives at byte ((c ^ (r&15)) << 3).
__device__ __forceinline__ bf16x8 read_frag8(const char* base, int r, int p0) {
    const char* rowp = base + r * 128;
    const int rr = r & 15;
    bf16x4 lo = *(const bf16x4*)(rowp + (((p0 + 0) ^ rr) << 3));
    bf16x4 hi4 = *(const bf16x4*)(rowp + (((p0 + 1) ^ rr) << 3));
    bf16x8 f;
    f[0] = lo[0]; f[1] = lo[1]; f[2] = lo[2]; f[3] = lo[3];
    f[4] = hi4[0]; f[5] = hi4[1]; f[6] = hi4[2]; f[7] = hi4[3];
    return f;
}

#if __has_builtin(__builtin_amdgcn_global_load_lds)
#define HAVE_GLLDS 1
typedef const __attribute__((address_space(1))) unsigned int* gas_t;
typedef __attribute__((address_space(3))) unsigned int* las_t;
__device__ __forceinline__ void gl_lds16(const void* g, void* l) {
    __builtin_amdgcn_global_load_lds((gas_t)g, (las_t)l, 16, 0, 0);
}
#else
#define HAVE_GLLDS 0
#endif

// ---------------- prepass: build bf16 tile images (swz8 layout) ----------------
__global__ __launch_bounds__(256)
void prep_kernel(const float* __restrict__ x, char* __restrict__ ws) {
    const int bh = blockIdx.y;
    const int tile = blockIdx.x;
    const int kv0 = tile * KVB;
    const int t = threadIdx.x;
    const int srow = t >> 2;        // 0..63
    const int scq = (t & 3) * 16;   // 0,16,32,48
    const float* __restrict__ X = x + (size_t)bh * SEQ * HD;
    char* __restrict__ img = ws + ((size_t)bh * NTILE + tile) * PAIR_BYTES;

    const int rr = srow & 15;
    const int p = scq >> 2;         // base chunk: 0,4,8,12

    // K image: [kv][d] bf16, swz8 rows
    {
        const float* src = X + (size_t)(kv0 + srow) * HD + scq;
        float4 a = *(const float4*)(src);
        float4 b = *(const float4*)(src + 4);
        float4 c = *(const float4*)(src + 8);
        float4 d = *(const float4*)(src + 12);
        bf16x4 k0, k1, k2, k3;
        k0[0] = (__bf16)a.x; k0[1] = (__bf16)a.y; k0[2] = (__bf16)a.z; k0[3] = (__bf16)a.w;
        k1[0] = (__bf16)b.x; k1[1] = (__bf16)b.y; k1[2] = (__bf16)b.z; k1[3] = (__bf16)b.w;
        k2[0] = (__bf16)c.x; k2[1] = (__bf16)c.y; k2[2] = (__bf16)c.z; k2[3] = (__bf16)c.w;
        k3[0] = (__bf16)d.x; k3[1] = (__bf16)d.y; k3[2] = (__bf16)d.z; k3[3] = (__bf16)d.w;
        char* rowp = img + srow * 128;
        *(bf16x4*)(rowp + (((p + 0) ^ rr) << 3)) = k0;
        *(bf16x4*)(rowp + (((p + 1) ^ rr) << 3)) = k1;
        *(bf16x4*)(rowp + (((p + 2) ^ rr) << 3)) = k2;
        *(bf16x4*)(rowp + (((p + 3) ^ rr) << 3)) = k3;
    }
    // VT image: [d][kv] bf16, swz8 rows (row = d = srow, cols = kv)
    {
        bf16x4 g0, g1, g2, g3;
#pragma unroll
        for (int j = 0; j < 4; ++j) {
            g0[j] = (__bf16)X[(size_t)(kv0 + scq + j) * HD + srow];
            g1[j] = (__bf16)X[(size_t)(kv0 + scq + 4 + j) * HD + srow];
            g2[j] = (__bf16)X[(size_t)(kv0 + scq + 8 + j) * HD + srow];
            g3[j] = (__bf16)X[(size_t)(kv0 + scq + 12 + j) * HD + srow];
        }
        char* rowp = img + IMG_BYTES + srow * 128;
        *(bf16x4*)(rowp + (((p + 0) ^ rr) << 3)) = g0;
        *(bf16x4*)(rowp + (((p + 1) ^ rr) << 3)) = g1;
        *(bf16x4*)(rowp + (((p + 2) ^ rr) << 3)) = g2;
        *(bf16x4*)(rowp + (((p + 3) ^ rr) << 3)) = g3;
    }
}

// ---------------- main fused attention (single pass, static shift) ----------
__global__ __launch_bounds__(256, 4)
void attn_img_kernel(const float* __restrict__ x, const char* __restrict__ ws,
                     float* __restrict__ outp) {
    __shared__ __align__(16) char kbuf[2][IMG_BYTES];
    __shared__ __align__(16) char vbuf[2][IMG_BYTES];

    // T1 XCD swizzle over 512 (bijective, 512 % 8 == 0)
    const int wg = blockIdx.x;
    const int sid = (wg & 7) * 64 + (wg >> 3);
    const int bh = sid >> 4;
    const int q0 = (sid & 15) * QPB;

    const float* __restrict__ X = x + (size_t)bh * SEQ * HD;
    const char* __restrict__ wsb = ws + (size_t)bh * NTILE * PAIR_BYTES;

    const int t = threadIdx.x;
    const int wave = t >> 6;
    const int lane = t & 63;
    const int ln = lane & 31;   // own q row; also d-col index in O
    const int hi = lane >> 5;

    const int qbase = q0 + wave * 32;

    // ---- hoist Q B-frags (q=ln, d = dt*16 + hi*8 + b), pre-scaled by log2e;
    //      static shift m = log2e * |q_row|^2 (exact; diag bounds exponent) ----
    const float SCL = 1.4426950408889634f;
    bf16x8 qf[4];
    float m = 0.f;
    {
        const float* qsrc = X + (size_t)(qbase + ln) * HD;
#pragma unroll
        for (int j = 0; j < 16; ++j) {
            float4 v = *(const float4*)(qsrc + j * 4);
            m += v.x * v.x + v.y * v.y + v.z * v.z + v.w * v.w;
        }
        m *= SCL;
#pragma unroll
        for (int dt = 0; dt < 4; ++dt) {
            const float* s8 = qsrc + dt * 16 + hi * 8;
            float4 a = *(const float4*)s8;
            float4 b = *(const float4*)(s8 + 4);
            bf16x8 f;
            f[0] = (__bf16)(a.x * SCL); f[1] = (__bf16)(a.y * SCL);
            f[2] = (__bf16)(a.z * SCL); f[3] = (__bf16)(a.w * SCL);
            f[4] = (__bf16)(b.x * SCL); f[5] = (__bf16)(b.y * SCL);
            f[6] = (__bf16)(b.z * SCL); f[7] = (__bf16)(b.w * SCL);
            qf[dt] = f;
        }
    }
    const float negm = -m;

    // ones B-frag for the l-accumulating MFMA (bf16 1.0 = 0x3F80)
    bf16x8 onef;
    {
        u32x4v w;
        w[0] = 0x3F803F80u; w[1] = 0x3F803F80u; w[2] = 0x3F803F80u; w[3] = 0x3F803F80u;
        onef = __builtin_bit_cast(bf16x8, w);
    }

    f32x16 acc0, acc1, lac;
#pragma unroll
    for (int i = 0; i < 16; ++i) { acc0[i] = 0.f; acc1[i] = 0.f; lac[i] = 0.f; }

    // ---- prologue: stage tile 0 (wave w copies 4KB chunk w of the pair) ----
#if HAVE_GLLDS
    {
        char* base = (wave & 2) ? &vbuf[0][(wave & 1) * 4096] : &kbuf[0][(wave & 1) * 4096];
        const char* sp = wsb + wave * 4096 + lane * 16;
#pragma unroll
        for (int j = 0; j < 4; ++j)
            gl_lds16(sp + j * 1024, base + j * 1024);
    }
#else
    {
        const char* img = wsb;
#pragma unroll
        for (int q = 0; q < 4; ++q) {
            bf16x8 d0 = *(const bf16x8*)(img + q * 4096 + t * 16);
            char* dst = (q & 2) ? &vbuf[0][(q & 1) * 4096] : &kbuf[0][(q & 1) * 4096];
            *(bf16x8*)&dst[t * 16] = d0;
        }
    }
#endif
    __syncthreads();

    for (int it = 0; it < NTILE; ++it) {
        const int cur = it & 1;

#if HAVE_GLLDS
        if (it + 1 < NTILE) {
            const char* img = wsb + (size_t)(it + 1) * PAIR_BYTES;
            char* base = (wave & 2) ? &vbuf[cur ^ 1][(wave & 1) * 4096]
                                    : &kbuf[cur ^ 1][(wave & 1) * 4096];
            const char* sp = img + wave * 4096 + lane * 16;
#pragma unroll
            for (int j = 0; j < 4; ++j)
                gl_lds16(sp + j * 1024, base + j * 1024);
        }
#else
        bf16x8 n0, n1, n2, n3;
        if (it + 1 < NTILE) {
            const char* img = wsb + (size_t)(it + 1) * PAIR_BYTES;
            n0 = *(const bf16x8*)(img + t * 16);
            n1 = *(const bf16x8*)(img + 4096 + t * 16);
            n2 = *(const bf16x8*)(img + 8192 + t * 16);
            n3 = *(const bf16x8*)(img + 12288 + t * 16);
        }
#endif

        const char* kb = kbuf[cur];
        const char* vb = vbuf[cur];

        // ---- S^T = mfma(K, Q) with C-init = -m (folds the shift) ----
        f32x16 s0, s1;
#pragma unroll
        for (int i = 0; i < 16; ++i) { s0[i] = negm; s1[i] = negm; }
        __builtin_amdgcn_s_setprio(1);
#pragma unroll
        for (int dt = 0; dt < 4; ++dt) {
            const int p0 = dt * 4 + hi * 2;
            bf16x8 kf0 = read_frag8(kb, ln, p0);
            s0 = __builtin_amdgcn_mfma_f32_32x32x16_bf16(kf0, qf[dt], s0, 0, 0, 0);
            bf16x8 kf1 = read_frag8(kb, 32 + ln, p0);
            s1 = __builtin_amdgcn_mfma_f32_32x32x16_bf16(kf1, qf[dt], s1, 0, 0, 0);
        }
        __builtin_amdgcn_s_setprio(0);

        // ---- static-shift softmax: e = exp2(s); no max, no sum chain ----
        f32x16 e0, e1;
#pragma unroll
        for (int i = 0; i < 16; ++i) {
            e0[i] = fexp2(s0[i]);
            e1[i] = fexp2(s1[i]);
        }

        // ---- P -> PA frags in-register (cvt_pk + permlane32_swap) ----
        bf16x8 pa[4];
#pragma unroll
        for (int kt = 0; kt < 4; ++kt) {
            const f32x16& e = (kt & 2) ? e1 : e0;
            const int sx = 8 * (kt & 1);
            unsigned wA = pk_bf16(e[sx + 0], e[sx + 1]);
            unsigned wB = pk_bf16(e[sx + 2], e[sx + 3]);
            unsigned wC = pk_bf16(e[sx + 4], e[sx + 5]);
            unsigned wD = pk_bf16(e[sx + 6], e[sx + 7]);
            asm("v_permlane32_swap_b32 %0, %1" : "+v"(wA), "+v"(wC));
            asm("v_permlane32_swap_b32 %0, %1" : "+v"(wB), "+v"(wD));
            u32x4v w;
            w[0] = wA; w[1] = wB; w[2] = wC; w[3] = wD;
            pa[kt] = __builtin_bit_cast(bf16x8, w);
        }

        // ---- O += P V ; l_acc += P * ones (row sums, epilogue layout) ----
        __builtin_amdgcn_s_setprio(1);
#pragma unroll
        for (int kt = 0; kt < 4; ++kt) {
            const int p0 = kt * 4 + hi * 2;
            bf16x8 vf0 = read_frag8(vb, ln, p0);
            acc0 = __builtin_amdgcn_mfma_f32_32x32x16_bf16(pa[kt], vf0, acc0, 0, 0, 0);
            bf16x8 vf1 = read_frag8(vb, 32 + ln, p0);
            acc1 = __builtin_amdgcn_mfma_f32_32x32x16_bf16(pa[kt], vf1, acc1, 0, 0, 0);
            lac = __builtin_amdgcn_mfma_f32_32x32x16_bf16(pa[kt], onef, lac, 0, 0, 0);
        }
        __builtin_amdgcn_s_setprio(0);

#if !HAVE_GLLDS
        if (it + 1 < NTILE) {
            const int nxt = cur ^ 1;
            *(bf16x8*)&kbuf[nxt][t * 16] = n0;
            *(bf16x8*)&kbuf[nxt][4096 + t * 16] = n1;
            *(bf16x8*)&vbuf[nxt][t * 16] = n2;
            *(bf16x8*)&vbuf[nxt][4096 + t * 16] = n3;
        }
#endif
        __syncthreads();
    }

    // ---- epilogue: normalize (l for row crow(r,hi) is lac[r]) and store ----
    float* Op = outp + (size_t)bh * SEQ * HD;
#pragma unroll
    for (int r = 0; r < 16; ++r) {
        const int qr = (r & 3) + 8 * (r >> 2) + 4 * hi;
        const float il = 1.f / lac[r];
        float* dst = Op + (size_t)(qbase + qr) * HD + ln;
        dst[0]  = acc0[r] * il;
        dst[32] = acc1[r] * il;
    }
}

// ---------------- fallback (R1-style kernel, no workspace needed) ----------------
__global__ __launch_bounds__(256, 2)
void attn_fwd_kernel(const float* __restrict__ x, float* __restrict__ out) {
    __shared__ __align__(16) char k_lds[KVB * HD * 2];
    __shared__ __align__(16) char vt_lds[HD * KVB * 2];
    __shared__ __align__(16) char p_lds2[4][2][16 * KVB * 2];

    const int bh = blockIdx.y;
    const int q0 = blockIdx.x * 128;
    const float* __restrict__ X = x + (size_t)bh * SEQ * HD;
    float* __restrict__ Op = out + (size_t)bh * SEQ * HD;

    const int t = threadIdx.x;
    const int wave = t >> 6;
    const int lane = t & 63;
    const int lgrp = lane >> 4;
    const int lid = lane & 15;

    bf16x8 qf[2][2];
#pragma unroll
    for (int rt = 0; rt < 2; ++rt) {
        const int row = q0 + wave * 32 + rt * 16 + lid;
#pragma unroll
        for (int kc = 0; kc < 2; ++kc) {
            const float* src = X + (size_t)row * HD + kc * 32 + lgrp * 8;
            float4 a = *(const float4*)src;
            float4 b = *(const float4*)(src + 4);
            bf16x8 f;
            f[0] = (__bf16)a.x; f[1] = (__bf16)a.y; f[2] = (__bf16)a.z; f[3] = (__bf16)a.w;
            f[4] = (__bf16)b.x; f[5] = (__bf16)b.y; f[6] = (__bf16)b.z; f[7] = (__bf16)b.w;
            qf[rt][kc] = f;
        }
    }

    f32x4 acc[2][4];
    float m[2][4], l[2][4];
#pragma unroll
    for (int rt = 0; rt < 2; ++rt)
#pragma unroll
        for (int i = 0; i < 4; ++i) {
            acc[rt][i][0] = 0.f; acc[rt][i][1] = 0.f;
            acc[rt][i][2] = 0.f; acc[rt][i][3] = 0.f;
            m[rt][i] = -1e30f;
            l[rt][i] = 0.f;
        }

    const int srow = t >> 2;
    const int scq = (t & 3) * 16;

    for (int kv0 = 0; kv0 < SEQ; kv0 += KVB) {
        {
            const float* src = X + (size_t)(kv0 + srow) * HD + scq;
            float4 a = *(const float4*)(src);
            float4 b = *(const float4*)(src + 4);
            float4 c = *(const float4*)(src + 8);
            float4 d = *(const float4*)(src + 12);
            bf16x8 f0, f1;
            f0[0] = (__bf16)a.x; f0[1] = (__bf16)a.y; f0[2] = (__bf16)a.z; f0[3] = (__bf16)a.w;
            f0[4] = (__bf16)b.x; f0[5] = (__bf16)b.y; f0[6] = (__bf16)b.z; f0[7] = (__bf16)b.w;
            f1[0] = (__bf16)c.x; f1[1] = (__bf16)c.y; f1[2] = (__bf16)c.z; f1[3] = (__bf16)c.w;
            f1[4] = (__bf16)d.x; f1[5] = (__bf16)d.y; f1[6] = (__bf16)d.z; f1[7] = (__bf16)d.w;
            *(bf16x8*)&k_lds[swz(srow, srow * 128 + scq * 2)] = f0;
            *(bf16x8*)&k_lds[swz(srow, srow * 128 + scq * 2 + 16)] = f1;
        }
        {
            bf16x8 g0, g1;
#pragma unroll
            for (int j = 0; j < 8; ++j)
                g0[j] = (__bf16)X[(size_t)(kv0 + scq + j) * HD + srow];
#pragma unroll
            for (int j = 0; j < 8; ++j)
                g1[j] = (__bf16)X[(size_t)(kv0 + scq + 8 + j) * HD + srow];
            *(bf16x8*)&vt_lds[swz(srow, srow * 128 + scq * 2)] = g0;
            *(bf16x8*)&vt_lds[swz(srow, srow * 128 + scq * 2 + 16)] = g1;
        }
        __syncthreads();

#pragma unroll
        for (int rt = 0; rt < 2; ++rt) {
            f32x4 s[4];
#pragma unroll
            for (int kt = 0; kt < 4; ++kt) {
                f32x4 z = {0.f, 0.f, 0.f, 0.f};
#pragma unroll
                for (int kc = 0; kc < 2; ++kc) {
                    const int krow = kt * 16 + lid;
                    bf16x8 kfr = *(const bf16x8*)&k_lds[swz(krow, krow * 128 + (kc * 32 + lgrp * 8) * 2)];
                    z = __builtin_amdgcn_mfma_f32_16x16x32_bf16(qf[rt][kc], kfr, z, 0, 0, 0);
                }
                s[kt] = z;
            }

            char* pl = p_lds2[wave][rt];
#pragma unroll
            for (int r = 0; r < 4; ++r) {
                float mxv = fmaxf(fmaxf(s[0][r], s[1][r]), fmaxf(s[2][r], s[3][r]));
                mxv = fmaxf(mxv, __shfl_xor(mxv, 1));
                mxv = fmaxf(mxv, __shfl_xor(mxv, 2));
                mxv = fmaxf(mxv, __shfl_xor(mxv, 4));
                mxv = fmaxf(mxv, __shfl_xor(mxv, 8));
                const float mold = m[rt][r];
                const float mnew = fmaxf(mold, mxv);
                const float alpha = __expf(mold - mnew);
                const int prow = lgrp * 4 + r;
                float psum = 0.f;
#pragma unroll
                for (int kt = 0; kt < 4; ++kt) {
                    float p = __expf(s[kt][r] - mnew);
                    psum += p;
                    *(__bf16*)&pl[swz(prow, prow * 128 + (kt * 16 + lid) * 2)] = (__bf16)p;
                }
                psum += __shfl_xor(psum, 1);
                psum += __shfl_xor(psum, 2);
                psum += __shfl_xor(psum, 4);
                psum += __shfl_xor(psum, 8);
                l[rt][r] = l[rt][r] * alpha + psum;
                m[rt][r] = mnew;
#pragma unroll
                for (int ct = 0; ct < 4; ++ct)
                    acc[rt][ct][r] *= alpha;
            }

#pragma unroll
            for (int kc = 0; kc < 2; ++kc) {
                bf16x8 pfr = *(const bf16x8*)&pl[swz(lid, lid * 128 + (kc * 32 + lgrp * 8) * 2)];
#pragma unroll
                for (int ct = 0; ct < 4; ++ct) {
                    const int vrow = ct * 16 + lid;
                    bf16x8 vf = *(const bf16x8*)&vt_lds[swz(vrow, vrow * 128 + (kc * 32 + lgrp * 8) * 2)];
                    acc[rt][ct] = __builtin_amdgcn_mfma_f32_16x16x32_bf16(pfr, vf, acc[rt][ct], 0, 0, 0);
                }
            }
        }
        __syncthreads();
    }

#pragma unroll
    for (int rt = 0; rt < 2; ++rt)
#pragma unroll
        for (int r = 0; r < 4; ++r) {
            const float inv = 1.f / l[rt][r];
            const int row = q0 + wave * 32 + rt * 16 + lgrp * 4 + r;
            float* dst = Op + (size_t)row * HD + lid;
#pragma unroll
            for (int ct = 0; ct < 4; ++ct)
                dst[ct * 16] = acc[rt][ct][r] * inv;
        }
}

extern "C" void kernel_launch(void* const* d_in, const int* in_sizes, int n_in,
                              void* d_out, int out_size, void* d_ws, size_t ws_size,
                              hipStream_t stream) {
    const float* x = (const float*)d_in[0];
    float* out = (float*)d_out;
    char* ws = (char*)d_ws;
    if (ws_size >= WS_IMG) {
        dim3 pgrid(NTILE, NBH);
        hipLaunchKernelGGL(prep_kernel, pgrid, dim3(256), 0, stream, x, ws);
        hipLaunchKernelGGL(attn_img_kernel, dim3(512), dim3(256), 0, stream,
                           x, ws, out);
    } else {
        dim3 grid(SEQ / 128, NBH);
        hipLaunchKernelGGL(attn_fwd_kernel, grid, dim3(256), 0, stream, x, out);
    }
}

// Round 10
// 71.104 us; speedup vs baseline: 1.2043x; 1.2043x over previous
//
#include <hip/hip_runtime.h>
#include <hip/hip_bf16.h>
#include <stdint.h>

// MatmulAttention: x = [2,16,2048,64] f32, q=k=v=x, no 1/sqrt(d) scale.
// out = softmax(q k^T) v, f32.
// R10 = R8's verified compute (swz8 frag reads, static-shift exp2(s-m),
// cvt_pk+permlane P transpose, l-sum+shfl), single pass (512 blocks), with
// the per-iteration __syncthreads() drain replaced by a 3-buffer depth-2
// DMA pipeline: counted s_waitcnt vmcnt(4) + raw s_barrier (T3/T4, m201
// pattern). Only the last iteration drains vmcnt to 0.
// R9's lac/negm reverted (lengthened dep chain, -17us regression).

typedef __bf16 bf16x8 __attribute__((ext_vector_type(8)));
typedef __bf16 bf16x4 __attribute__((ext_vector_type(4)));
typedef __bf16 bf16x2 __attribute__((ext_vector_type(2)));
typedef float f32x4 __attribute__((ext_vector_type(4)));
typedef float f32x16 __attribute__((ext_vector_type(16)));
typedef unsigned int u32x4v __attribute__((ext_vector_type(4)));

#define SEQ 2048
#define HD 64
#define KVB 64
#define NBH 32
#define NTILE (SEQ / KVB)        // 32 kv tiles
#define IMG_BYTES 8192           // one 64x64 bf16 tile image
#define PAIR_BYTES 16384         // K image + VT image
#define IMG_TOT ((size_t)NBH * NTILE * PAIR_BYTES)          // 16 MB
#define WS_IMG IMG_TOT

#define QPB 128                  // q rows per block (32 per wave, 4 waves)

// 16B swizzle (R1 fallback kernel only)
__device__ __forceinline__ int swz(int row, int byteoff) {
    return byteoff ^ ((row & 7) << 4);
}

__device__ __forceinline__ float fexp2(float x) {
    float r;
    asm("v_exp_f32 %0, %1" : "=v"(r) : "v"(x));
    return r;
}

__device__ __forceinline__ unsigned pk_bf16(float a, float b) {
    bf16x2 v;
    v[0] = (__bf16)a;
    v[1] = (__bf16)b;
    return __builtin_bit_cast(unsigned, v);
}

// swz8: chunk c (8B, cols 4c..4c+3) of row r lives at byte ((c ^ (r&15)) << 3).
__device__ __forceinline__ bf16x8 read_frag8(const char* base, int r, int p0) {
    const char* rowp = base + r * 128;
    const int rr = r & 15;
    bf16x4 lo = *(const bf16x4*)(rowp + (((p0 + 0) ^ rr) << 3));
    bf16x4 hi4 = *(const bf16x4*)(rowp + (((p0 + 1) ^ rr) << 3));
    bf16x8 f;
    f[0] = lo[0]; f[1] = lo[1]; f[2] = lo[2]; f[3] = lo[3];
    f[4] = hi4[0]; f[5] = hi4[1]; f[6] = hi4[2]; f[7] = hi4[3];
    return f;
}

#if __has_builtin(__builtin_amdgcn_global_load_lds)
#define HAVE_GLLDS 1
typedef const __attribute__((address_space(1))) unsigned int* gas_t;
typedef __attribute__((address_space(3))) unsigned int* las_t;
__device__ __forceinline__ void gl_lds16(const void* g, void* l) {
    __builtin_amdgcn_global_load_lds((gas_t)g, (las_t)l, 16, 0, 0);
}
#else
#define HAVE_GLLDS 0
#endif

// ---------------- prepass: build bf16 tile images (swz8 layout) ----------------
__global__ __launch_bounds__(256)
void prep_kernel(const float* __restrict__ x, char* __restrict__ ws) {
    const int bh = blockIdx.y;
    const int tile = blockIdx.x;
    const int kv0 = tile * KVB;
    const int t = threadIdx.x;
    const int srow = t >> 2;        // 0..63
    const int scq = (t & 3) * 16;   // 0,16,32,48
    const float* __restrict__ X = x + (size_t)bh * SEQ * HD;
    char* __restrict__ img = ws + ((size_t)bh * NTILE + tile) * PAIR_BYTES;

    const int rr = srow & 15;
    const int p = scq >> 2;         // base chunk: 0,4,8,12

    // K image: [kv][d] bf16, swz8 rows
    {
        const float* src = X + (size_t)(kv0 + srow) * HD + scq;
        float4 a = *(const float4*)(src);
        float4 b = *(const float4*)(src + 4);
        float4 c = *(const float4*)(src + 8);
        float4 d = *(const float4*)(src + 12);
        bf16x4 k0, k1, k2, k3;
        k0[0] = (__bf16)a.x; k0[1] = (__bf16)a.y; k0[2] = (__bf16)a.z; k0[3] = (__bf16)a.w;
        k1[0] = (__bf16)b.x; k1[1] = (__bf16)b.y; k1[2] = (__bf16)b.z; k1[3] = (__bf16)b.w;
        k2[0] = (__bf16)c.x; k2[1] = (__bf16)c.y; k2[2] = (__bf16)c.z; k2[3] = (__bf16)c.w;
        k3[0] = (__bf16)d.x; k3[1] = (__bf16)d.y; k3[2] = (__bf16)d.z; k3[3] = (__bf16)d.w;
        char* rowp = img + srow * 128;
        *(bf16x4*)(rowp + (((p + 0) ^ rr) << 3)) = k0;
        *(bf16x4*)(rowp + (((p + 1) ^ rr) << 3)) = k1;
        *(bf16x4*)(rowp + (((p + 2) ^ rr) << 3)) = k2;
        *(bf16x4*)(rowp + (((p + 3) ^ rr) << 3)) = k3;
    }
    // VT image: [d][kv] bf16, swz8 rows (row = d = srow, cols = kv)
    {
        bf16x4 g0, g1, g2, g3;
#pragma unroll
        for (int j = 0; j < 4; ++j) {
            g0[j] = (__bf16)X[(size_t)(kv0 + scq + j) * HD + srow];
            g1[j] = (__bf16)X[(size_t)(kv0 + scq + 4 + j) * HD + srow];
            g2[j] = (__bf16)X[(size_t)(kv0 + scq + 8 + j) * HD + srow];
            g3[j] = (__bf16)X[(size_t)(kv0 + scq + 12 + j) * HD + srow];
        }
        char* rowp = img + IMG_BYTES + srow * 128;
        *(bf16x4*)(rowp + (((p + 0) ^ rr) << 3)) = g0;
        *(bf16x4*)(rowp + (((p + 1) ^ rr) << 3)) = g1;
        *(bf16x4*)(rowp + (((p + 2) ^ rr) << 3)) = g2;
        *(bf16x4*)(rowp + (((p + 3) ^ rr) << 3)) = g3;
    }
}

// ---------------- main fused attention (3-buffer counted-vmcnt pipeline) ------
__global__ __launch_bounds__(256, 2)
void attn_img_kernel(const float* __restrict__ x, const char* __restrict__ ws,
                     float* __restrict__ outp) {
#if HAVE_GLLDS
    __shared__ __align__(16) char lds3[3][PAIR_BYTES];   // 48 KB
#else
    __shared__ __align__(16) char lds3[2][PAIR_BYTES];   // fallback dbuf
#endif

    // T1 XCD swizzle over 512 (bijective, 512 % 8 == 0)
    const int wg = blockIdx.x;
    const int sid = (wg & 7) * 64 + (wg >> 3);
    const int bh = sid >> 4;
    const int q0 = (sid & 15) * QPB;

    const float* __restrict__ X = x + (size_t)bh * SEQ * HD;
    const char* __restrict__ wsb = ws + (size_t)bh * NTILE * PAIR_BYTES;

    const int t = threadIdx.x;
    const int wave = t >> 6;
    const int lane = t & 63;
    const int ln = lane & 31;   // own q row; also d-col index in O
    const int hi = lane >> 5;

    const int qbase = q0 + wave * 32;

    // ---- issue DMA for tiles 0 and 1 FIRST (hides under Q-hoist) ----
#if HAVE_GLLDS
    {
        const char* sp0 = wsb + wave * 4096 + lane * 16;
#pragma unroll
        for (int j = 0; j < 4; ++j)
            gl_lds16(sp0 + j * 1024, &lds3[0][wave * 4096 + j * 1024] + lane * 16);
        const char* sp1 = wsb + PAIR_BYTES + wave * 4096 + lane * 16;
#pragma unroll
        for (int j = 0; j < 4; ++j)
            gl_lds16(sp1 + j * 1024, &lds3[1][wave * 4096 + j * 1024] + lane * 16);
    }
#endif

    // ---- hoist Q B-frags (q=ln, d = dt*16 + hi*8 + b), pre-scaled by log2e;
    //      static shift m = log2e * |q_row|^2 (exact; diag bounds exponent) ----
    const float SCL = 1.4426950408889634f;
    bf16x8 qf[4];
    float m = 0.f;
    {
        const float* qsrc = X + (size_t)(qbase + ln) * HD;
#pragma unroll
        for (int j = 0; j < 16; ++j) {
            float4 v = *(const float4*)(qsrc + j * 4);
            m += v.x * v.x + v.y * v.y + v.z * v.z + v.w * v.w;
        }
        m *= SCL;
#pragma unroll
        for (int dt = 0; dt < 4; ++dt) {
            const float* s8 = qsrc + dt * 16 + hi * 8;
            float4 a = *(const float4*)s8;
            float4 b = *(const float4*)(s8 + 4);
            bf16x8 f;
            f[0] = (__bf16)(a.x * SCL); f[1] = (__bf16)(a.y * SCL);
            f[2] = (__bf16)(a.z * SCL); f[3] = (__bf16)(a.w * SCL);
            f[4] = (__bf16)(b.x * SCL); f[5] = (__bf16)(b.y * SCL);
            f[6] = (__bf16)(b.z * SCL); f[7] = (__bf16)(b.w * SCL);
            qf[dt] = f;
        }
    }

    f32x16 acc0, acc1;
#pragma unroll
    for (int i = 0; i < 16; ++i) { acc0[i] = 0.f; acc1[i] = 0.f; }
    float l = 0.f;

#if !HAVE_GLLDS
    // reg-staged prologue for the no-DMA fallback
    {
        const char* img = wsb;
#pragma unroll
        for (int q = 0; q < 4; ++q) {
            bf16x8 d0 = *(const bf16x8*)(img + q * 4096 + t * 16);
            *(bf16x8*)&lds3[0][q * 4096 + t * 16] = d0;
        }
    }
    __syncthreads();
#endif

    for (int it = 0; it < NTILE; ++it) {
#if HAVE_GLLDS
        // ---- counted-vmcnt sync: tile it's 4 loads landed; next tile's 4
        //      stay in flight. Full drain only on the last iteration. ----
        if (it + 1 < NTILE) {
            asm volatile("s_waitcnt vmcnt(4)" ::: "memory");
        } else {
            asm volatile("s_waitcnt vmcnt(0)" ::: "memory");
        }
        __builtin_amdgcn_s_barrier();
        __builtin_amdgcn_sched_barrier(0);

        // ---- issue DMA for tile it+2 into buf[(it+2)%3] (freed by barrier) --
        if (it + 2 < NTILE) {
            const char* img = wsb + (size_t)(it + 2) * PAIR_BYTES;
            char* dst = &lds3[(it + 2) % 3][wave * 4096] + lane * 16;
            const char* sp = img + wave * 4096 + lane * 16;
#pragma unroll
            for (int j = 0; j < 4; ++j)
                gl_lds16(sp + j * 1024, dst + j * 1024);
        }
        const char* kb = lds3[it % 3];
#else
        bf16x8 n0, n1, n2, n3;
        if (it + 1 < NTILE) {
            const char* img = wsb + (size_t)(it + 1) * PAIR_BYTES;
            n0 = *(const bf16x8*)(img + t * 16);
            n1 = *(const bf16x8*)(img + 4096 + t * 16);
            n2 = *(const bf16x8*)(img + 8192 + t * 16);
            n3 = *(const bf16x8*)(img + 12288 + t * 16);
        }
        const char* kb = lds3[it & 1];
#endif
        const char* vb = kb + IMG_BYTES;

        // ---- S^T = mfma(K, Q): col = q = ln, rows = kv reg-indexed ----
        f32x16 s0, s1;
#pragma unroll
        for (int i = 0; i < 16; ++i) { s0[i] = 0.f; s1[i] = 0.f; }
        __builtin_amdgcn_s_setprio(1);
#pragma unroll
        for (int dt = 0; dt < 4; ++dt) {
            const int p0 = dt * 4 + hi * 2;
            bf16x8 kf0 = read_frag8(kb, ln, p0);
            s0 = __builtin_amdgcn_mfma_f32_32x32x16_bf16(kf0, qf[dt], s0, 0, 0, 0);
            bf16x8 kf1 = read_frag8(kb, 32 + ln, p0);
            s1 = __builtin_amdgcn_mfma_f32_32x32x16_bf16(kf1, qf[dt], s1, 0, 0, 0);
        }
        __builtin_amdgcn_s_setprio(0);

        // ---- static-shift softmax: e = exp2(s - m); no max, no rescale ----
        f32x16 e0, e1;
#pragma unroll
        for (int i = 0; i < 16; ++i) {
            e0[i] = fexp2(s0[i] - m);
            e1[i] = fexp2(s1[i] - m);
        }
        float ps = 0.f;
#pragma unroll
        for (int i = 0; i < 16; ++i) ps += e0[i] + e1[i];
        ps += __shfl_xor(ps, 32);
        l += ps;

        // ---- P -> PA frags in-register (cvt_pk + permlane32_swap) ----
        bf16x8 pa[4];
#pragma unroll
        for (int kt = 0; kt < 4; ++kt) {
            const f32x16& e = (kt & 2) ? e1 : e0;
            const int sx = 8 * (kt & 1);
            unsigned wA = pk_bf16(e[sx + 0], e[sx + 1]);
            unsigned wB = pk_bf16(e[sx + 2], e[sx + 3]);
            unsigned wC = pk_bf16(e[sx + 4], e[sx + 5]);
            unsigned wD = pk_bf16(e[sx + 6], e[sx + 7]);
            asm("v_permlane32_swap_b32 %0, %1" : "+v"(wA), "+v"(wC));
            asm("v_permlane32_swap_b32 %0, %1" : "+v"(wB), "+v"(wD));
            u32x4v w;
            w[0] = wA; w[1] = wB; w[2] = wC; w[3] = wD;
            pa[kt] = __builtin_bit_cast(bf16x8, w);
        }

        // ---- O += P V ----
        __builtin_amdgcn_s_setprio(1);
#pragma unroll
        for (int kt = 0; kt < 4; ++kt) {
            const int p0 = kt * 4 + hi * 2;
            bf16x8 vf0 = read_frag8(vb, ln, p0);
            acc0 = __builtin_amdgcn_mfma_f32_32x32x16_bf16(pa[kt], vf0, acc0, 0, 0, 0);
            bf16x8 vf1 = read_frag8(vb, 32 + ln, p0);
            acc1 = __builtin_amdgcn_mfma_f32_32x32x16_bf16(pa[kt], vf1, acc1, 0, 0, 0);
        }
        __builtin_amdgcn_s_setprio(0);

#if !HAVE_GLLDS
        if (it + 1 < NTILE) {
            const int nxt = (it + 1) & 1;
            __syncthreads();
            *(bf16x8*)&lds3[nxt][t * 16] = n0;
            *(bf16x8*)&lds3[nxt][4096 + t * 16] = n1;
            *(bf16x8*)&lds3[nxt][8192 + t * 16] = n2;
            *(bf16x8*)&lds3[nxt][12288 + t * 16] = n3;
            __syncthreads();
        }
#endif
    }

    // ---- epilogue: normalize and store f32 ----
    float* Op = outp + (size_t)bh * SEQ * HD;
    const float invl = 1.f / l;
#pragma unroll
    for (int r = 0; r < 16; ++r) {
        const int qr = (r & 3) + 8 * (r >> 2) + 4 * hi;
        const float il = __shfl(invl, qr);
        float* dst = Op + (size_t)(qbase + qr) * HD + ln;
        dst[0]  = acc0[r] * il;
        dst[32] = acc1[r] * il;
    }
}

// ---------------- fallback (R1-style kernel, no workspace needed) ----------------
__global__ __launch_bounds__(256, 2)
void attn_fwd_kernel(const float* __restrict__ x, float* __restrict__ out) {
    __shared__ __align__(16) char k_lds[KVB * HD * 2];
    __shared__ __align__(16) char vt_lds[HD * KVB * 2];
    __shared__ __align__(16) char p_lds2[4][2][16 * KVB * 2];

    const int bh = blockIdx.y;
    const int q0 = blockIdx.x * 128;
    const float* __restrict__ X = x + (size_t)bh * SEQ * HD;
    float* __restrict__ Op = out + (size_t)bh * SEQ * HD;

    const int t = threadIdx.x;
    const int wave = t >> 6;
    const int lane = t & 63;
    const int lgrp = lane >> 4;
    const int lid = lane & 15;

    bf16x8 qf[2][2];
#pragma unroll
    for (int rt = 0; rt < 2; ++rt) {
        const int row = q0 + wave * 32 + rt * 16 + lid;
#pragma unroll
        for (int kc = 0; kc < 2; ++kc) {
            const float* src = X + (size_t)row * HD + kc * 32 + lgrp * 8;
            float4 a = *(const float4*)src;
            float4 b = *(const float4*)(src + 4);
            bf16x8 f;
            f[0] = (__bf16)a.x; f[1] = (__bf16)a.y; f[2] = (__bf16)a.z; f[3] = (__bf16)a.w;
            f[4] = (__bf16)b.x; f[5] = (__bf16)b.y; f[6] = (__bf16)b.z; f[7] = (__bf16)b.w;
            qf[rt][kc] = f;
        }
    }

    f32x4 acc[2][4];
    float m[2][4], l[2][4];
#pragma unroll
    for (int rt = 0; rt < 2; ++rt)
#pragma unroll
        for (int i = 0; i < 4; ++i) {
            acc[rt][i][0] = 0.f; acc[rt][i][1] = 0.f;
            acc[rt][i][2] = 0.f; acc[rt][i][3] = 0.f;
            m[rt][i] = -1e30f;
            l[rt][i] = 0.f;
        }

    const int srow = t >> 2;
    const int scq = (t & 3) * 16;

    for (int kv0 = 0; kv0 < SEQ; kv0 += KVB) {
        {
            const float* src = X + (size_t)(kv0 + srow) * HD + scq;
            float4 a = *(const float4*)(src);
            float4 b = *(const float4*)(src + 4);
            float4 c = *(const float4*)(src + 8);
            float4 d = *(const float4*)(src + 12);
            bf16x8 f0, f1;
            f0[0] = (__bf16)a.x; f0[1] = (__bf16)a.y; f0[2] = (__bf16)a.z; f0[3] = (__bf16)a.w;
            f0[4] = (__bf16)b.x; f0[5] = (__bf16)b.y; f0[6] = (__bf16)b.z; f0[7] = (__bf16)b.w;
            f1[0] = (__bf16)c.x; f1[1] = (__bf16)c.y; f1[2] = (__bf16)c.z; f1[3] = (__bf16)c.w;
            f1[4] = (__bf16)d.x; f1[5] = (__bf16)d.y; f1[6] = (__bf16)d.z; f1[7] = (__bf16)d.w;
            *(bf16x8*)&k_lds[swz(srow, srow * 128 + scq * 2)] = f0;
            *(bf16x8*)&k_lds[swz(srow, srow * 128 + scq * 2 + 16)] = f1;
        }
        {
            bf16x8 g0, g1;
#pragma unroll
            for (int j = 0; j < 8; ++j)
                g0[j] = (__bf16)X[(size_t)(kv0 + scq + j) * HD + srow];
#pragma unroll
            for (int j = 0; j < 8; ++j)
                g1[j] = (__bf16)X[(size_t)(kv0 + scq + 8 + j) * HD + srow];
            *(bf16x8*)&vt_lds[swz(srow, srow * 128 + scq * 2)] = g0;
            *(bf16x8*)&vt_lds[swz(srow, srow * 128 + scq * 2 + 16)] = g1;
        }
        __syncthreads();

#pragma unroll
        for (int rt = 0; rt < 2; ++rt) {
            f32x4 s[4];
#pragma unroll
            for (int kt = 0; kt < 4; ++kt) {
                f32x4 z = {0.f, 0.f, 0.f, 0.f};
#pragma unroll
                for (int kc = 0; kc < 2; ++kc) {
                    const int krow = kt * 16 + lid;
                    bf16x8 kfr = *(const bf16x8*)&k_lds[swz(krow, krow * 128 + (kc * 32 + lgrp * 8) * 2)];
                    z = __builtin_amdgcn_mfma_f32_16x16x32_bf16(qf[rt][kc], kfr, z, 0, 0, 0);
                }
                s[kt] = z;
            }

            char* pl = p_lds2[wave][rt];
#pragma unroll
            for (int r = 0; r < 4; ++r) {
                float mxv = fmaxf(fmaxf(s[0][r], s[1][r]), fmaxf(s[2][r], s[3][r]));
                mxv = fmaxf(mxv, __shfl_xor(mxv, 1));
                mxv = fmaxf(mxv, __shfl_xor(mxv, 2));
                mxv = fmaxf(mxv, __shfl_xor(mxv, 4));
                mxv = fmaxf(mxv, __shfl_xor(mxv, 8));
                const float mold = m[rt][r];
                const float mnew = fmaxf(mold, mxv);
                const float alpha = __expf(mold - mnew);
                const int prow = lgrp * 4 + r;
                float psum = 0.f;
#pragma unroll
                for (int kt = 0; kt < 4; ++kt) {
                    float p = __expf(s[kt][r] - mnew);
                    psum += p;
                    *(__bf16*)&pl[swz(prow, prow * 128 + (kt * 16 + lid) * 2)] = (__bf16)p;
                }
                psum += __shfl_xor(psum, 1);
                psum += __shfl_xor(psum, 2);
                psum += __shfl_xor(psum, 4);
                psum += __shfl_xor(psum, 8);
                l[rt][r] = l[rt][r] * alpha + psum;
                m[rt][r] = mnew;
#pragma unroll
                for (int ct = 0; ct < 4; ++ct)
                    acc[rt][ct][r] *= alpha;
            }

#pragma unroll
            for (int kc = 0; kc < 2; ++kc) {
                bf16x8 pfr = *(const bf16x8*)&pl[swz(lid, lid * 128 + (kc * 32 + lgrp * 8) * 2)];
#pragma unroll
                for (int ct = 0; ct < 4; ++ct) {
                    const int vrow = ct * 16 + lid;
                    bf16x8 vf = *(const bf16x8*)&vt_lds[swz(vrow, vrow * 128 + (kc * 32 + lgrp * 8) * 2)];
                    acc[rt][ct] = __builtin_amdgcn_mfma_f32_16x16x32_bf16(pfr, vf, acc[rt][ct], 0, 0, 0);
                }
            }
        }
        __syncthreads();
    }

#pragma unroll
    for (int rt = 0; rt < 2; ++rt)
#pragma unroll
        for (int r = 0; r < 4; ++r) {
            const float inv = 1.f / l[rt][r];
            const int row = q0 + wave * 32 + rt * 16 + lgrp * 4 + r;
            float* dst = Op + (size_t)row * HD + lid;
#pragma unroll
            for (int ct = 0; ct < 4; ++ct)
                dst[ct * 16] = acc[rt][ct][r] * inv;
        }
}

extern "C" void kernel_launch(void* const* d_in, const int* in_sizes, int n_in,
                              void* d_out, int out_size, void* d_ws, size_t ws_size,
                              hipStream_t stream) {
    const float* x = (const float*)d_in[0];
    float* out = (float*)d_out;
    char* ws = (char*)d_ws;
    if (ws_size >= WS_IMG) {
        dim3 pgrid(NTILE, NBH);
        hipLaunchKernelGGL(prep_kernel, pgrid, dim3(256), 0, stream, x, ws);
        hipLaunchKernelGGL(attn_img_kernel, dim3(512), dim3(256), 0, stream,
                           x, ws, out);
    } else {
        dim3 grid(SEQ / 128, NBH);
        hipLaunchKernelGGL(attn_fwd_kernel, grid, dim3(256), 0, stream, x, out);
    }
}